// Round 2
// baseline (6849.458 us; speedup 1.0000x reference)
//
#include <hip/hip_runtime.h>
#include <math.h>

// ---------------------------------------------------------------------------
// GeometricAttentionLayer: B=2, N=2048, C=64, MV=16, D=64, H=8, BLADE=9
// Workspace-adaptive streaming plan. All GEMMs fp32 (no fp32 MFMA on CDNA4;
// vector-ALU path — correctness-first round).
//   wb[(i*16+x), (j*16+y)] = sum_b w[j,i,b] * blade[b,x,y]
//   q/k built directly in IP-gathered layout (only 8/16 coords ever used).
//   O-projection GEMM accumulates straight into d_out (beta=0 on first head
//   group) so the 128 MB attn-out buffer is never materialized.
// ---------------------------------------------------------------------------

__constant__ int c_ip[8] = {0, 2, 3, 4, 8, 9, 10, 14};

// rows (i0+i)*16+x for i in [0,Ieff); cols j*16+y, j in [0,J)
// w is [J, Itot, 9]; wb is [Ieff*16, J*16]
__global__ __launch_bounds__(256) void build_wb_full(
    const float* __restrict__ w, const float* __restrict__ blade,
    float* __restrict__ wb, int Itot, int Ieff, int i0, int J)
{
  int ncol = J * 16;
  int total = Ieff * 16 * ncol;
  int idx = blockIdx.x * 256 + threadIdx.x;
  if (idx >= total) return;
  int col = idx % ncol;
  int row = idx / ncol;
  int j = col >> 4, y = col & 15;
  int i = i0 + (row >> 4), x = row & 15;
  const float* wp = w + ((size_t)j * Itot + i) * 9;
  const float* bp = blade + x * 16 + y;
  float s = 0.f;
#pragma unroll
  for (int b = 0; b < 9; b++) s += wp[b] * bp[b * 256];
  wb[idx] = s;
}

// IP-gathered, head-sliced: wb[(i*16+x), g*(D*8) + d*8 + e] for g in [0,nh)
// head h = h0+g, j = d*Htot + h, y = ip[e].  w is [D*Htot, I, 9].
__global__ __launch_bounds__(256) void build_wb_ip(
    const float* __restrict__ w, const float* __restrict__ blade,
    float* __restrict__ wb, int I, int D, int Htot, int h0, int nh)
{
  int ncol = D * nh * 8;
  int total = I * 16 * ncol;
  int idx = blockIdx.x * 256 + threadIdx.x;
  if (idx >= total) return;
  int col = idx % ncol;
  int row = idx / ncol;
  int e = col & 7;
  int dh = col >> 3;        // = g*D + d
  int d = dh % D;
  int g = dh / D;
  int j = d * Htot + (h0 + g);
  int i = row >> 4, x = row & 15;
  int y = c_ip[e];
  const float* wp = w + ((size_t)j * I + i) * 9;
  const float* bp = blade + x * 16 + y;
  float s = 0.f;
#pragma unroll
  for (int b = 0; b < 9; b++) s += wp[b] * bp[b * 256];
  wb[idx] = s;
}

// ---------------------------------------------------------------------------
// fp32 GEMM: C = alpha * A * op(B) (+ C if accum). 128x128 tile, BK=8,
// 256 thr, 8x8 micro. z-batched via sAz/sBz/sCz element strides.
// Requires M%128==0, N%128==0, K%8==0, 16B-aligned rows.
// ---------------------------------------------------------------------------
#define TM 128
#define TN 128
#define TK 8

template <bool TRANS_B>
__global__ __launch_bounds__(256) void gemm_f32(
    const float* __restrict__ A, int lda, long long sAz,
    const float* __restrict__ B, int ldb, long long sBz,
    float* __restrict__ C, int ldc, long long sCz,
    int K, float alpha, int accum)
{
  A += (size_t)blockIdx.z * sAz;
  B += (size_t)blockIdx.z * sBz;
  C += (size_t)blockIdx.z * sCz;

  __shared__ float As[TK][TM];
  __shared__ float Bs[TK][TN];

  const int tid = threadIdx.x;
  const int m0 = blockIdx.y * TM;
  const int n0 = blockIdx.x * TN;

  const int arow = tid >> 1, ac = (tid & 1) * 4;      // A: 128 rows x 8 k
  int brow, bc;
  if (TRANS_B) { brow = tid >> 1; bc = (tid & 1) * 4; }   // B: 128 n-rows x 8 k
  else         { brow = tid >> 5; bc = (tid & 31) * 4; }  // B: 8 k-rows x 128 n

  const int tx = tid & 15, ty = tid >> 4;

  float acc[8][8];
#pragma unroll
  for (int i = 0; i < 8; i++)
#pragma unroll
    for (int j = 0; j < 8; j++) acc[i][j] = 0.f;

  for (int k0 = 0; k0 < K; k0 += TK) {
    float4 av = *(const float4*)(A + (size_t)(m0 + arow) * lda + k0 + ac);
    float4 bv;
    if (TRANS_B) bv = *(const float4*)(B + (size_t)(n0 + brow) * ldb + k0 + bc);
    else         bv = *(const float4*)(B + (size_t)(k0 + brow) * ldb + n0 + bc);

    As[ac + 0][arow] = av.x;
    As[ac + 1][arow] = av.y;
    As[ac + 2][arow] = av.z;
    As[ac + 3][arow] = av.w;
    if (TRANS_B) {
      Bs[bc + 0][brow] = bv.x;
      Bs[bc + 1][brow] = bv.y;
      Bs[bc + 2][brow] = bv.z;
      Bs[bc + 3][brow] = bv.w;
    } else {
      *(float4*)&Bs[brow][bc] = bv;
    }
    __syncthreads();

#pragma unroll
    for (int kk = 0; kk < TK; kk++) {
      float4 a0 = *(const float4*)&As[kk][ty * 4];
      float4 a1 = *(const float4*)&As[kk][ty * 4 + 64];
      float4 b0 = *(const float4*)&Bs[kk][tx * 4];
      float4 b1 = *(const float4*)&Bs[kk][tx * 4 + 64];
      float a[8] = {a0.x, a0.y, a0.z, a0.w, a1.x, a1.y, a1.z, a1.w};
      float b[8] = {b0.x, b0.y, b0.z, b0.w, b1.x, b1.y, b1.z, b1.w};
#pragma unroll
      for (int i = 0; i < 8; i++)
#pragma unroll
        for (int j = 0; j < 8; j++) acc[i][j] += a[i] * b[j];
    }
    __syncthreads();
  }

#pragma unroll
  for (int i = 0; i < 8; i++) {
    int r = m0 + ty * 4 + (i & 3) + (i >> 2) * 64;
    size_t roff = (size_t)r * ldc;
    float4 v0 = make_float4(acc[i][0] * alpha, acc[i][1] * alpha,
                            acc[i][2] * alpha, acc[i][3] * alpha);
    float4 v1 = make_float4(acc[i][4] * alpha, acc[i][5] * alpha,
                            acc[i][6] * alpha, acc[i][7] * alpha);
    float* p0 = C + roff + n0 + tx * 4;
    float* p1 = C + roff + n0 + tx * 4 + 64;
    if (accum) {
      float4 c0 = *(const float4*)p0;
      float4 c1 = *(const float4*)p1;
      v0.x += c0.x; v0.y += c0.y; v0.z += c0.z; v0.w += c0.w;
      v1.x += c1.x; v1.y += c1.y; v1.z += c1.z; v1.w += c1.w;
    }
    *(float4*)p0 = v0;
    *(float4*)p1 = v1;
  }
}

// ---------------------------------------------------------------------------
// Row softmax in place over contiguous rows of length ncols.
// ---------------------------------------------------------------------------
__global__ __launch_bounds__(256) void softmax_rows(float* __restrict__ P, int ncols)
{
  float* p = P + (size_t)blockIdx.x * ncols;
  int tid = threadIdx.x;
  int wave = tid >> 6, lane = tid & 63;

  float m = -1e30f;
  for (int c = tid; c < ncols; c += 256) m = fmaxf(m, p[c]);
#pragma unroll
  for (int off = 32; off; off >>= 1) m = fmaxf(m, __shfl_xor(m, off, 64));
  __shared__ float sm[4];
  if (lane == 0) sm[wave] = m;
  __syncthreads();
  m = fmaxf(fmaxf(sm[0], sm[1]), fmaxf(sm[2], sm[3]));

  float s = 0.f;
  for (int c = tid; c < ncols; c += 256) {
    float e = expf(p[c] - m);
    p[c] = e;
    s += e;
  }
#pragma unroll
  for (int off = 32; off; off >>= 1) s += __shfl_xor(s, off, 64);
  __shared__ float ss[4];
  if (lane == 0) ss[wave] = s;
  __syncthreads();
  s = ss[0] + ss[1] + ss[2] + ss[3];
  float inv = 1.0f / s;
  for (int c = tid; c < ncols; c += 256) p[c] *= inv;
}

// ---------------------------------------------------------------------------
extern "C" void kernel_launch(void* const* d_in, const int* in_sizes, int n_in,
                              void* d_out, int out_size, void* d_ws, size_t ws_size,
                              hipStream_t stream)
{
  (void)in_sizes; (void)n_in; (void)out_size;
  const float* x     = (const float*)d_in[0];  // [4096, 1024]
  const float* blade = (const float*)d_in[1];  // [9,16,16]
  const float* w_q   = (const float*)d_in[2];  // [512,64,9]
  const float* w_k   = (const float*)d_in[3];  // [64,64,9]
  const float* w_v   = (const float*)d_in[4];  // [64,64,9]
  const float* w_o   = (const float*)d_in[5];  // [64,512,9]
  float* out = (float*)d_out;                  // [4096, 1024]
  float* ws = (float*)d_ws;

  const int Nn = 2048, Cc = 64, Dd = 64, Hh = 8;

  // --- pick (nh, qc) by workspace budget -----------------------------------
  // need(nh,qc) elements = fixed 7,864,320 + nh*4,718,592 + nh*qc*2048
  int nh = 1, qc = 128;
  {
    const size_t fixed = 7864320, per = 4718592;
    struct { int nh, qc; } tiers[] = {{8,2048},{8,512},{4,512},{2,512},{1,512},{1,128}};
    for (auto t : tiers) {
      size_t need = (fixed + (size_t)t.nh * per +
                     (size_t)t.nh * t.qc * 2048) * sizeof(float);
      if (ws_size >= need) { nh = t.nh; qc = t.qc; break; }
    }
  }

  // --- workspace layout (element offsets) ----------------------------------
  size_t OFF_WBK  = 0;                                   // [1024, 512]
  size_t OFF_WBV  = OFF_WBK + (size_t)1024 * 512;        // [1024, 1024]
  size_t OFF_KM   = OFF_WBV + (size_t)1024 * 1024;       // [4096, 512]
  size_t OFF_V    = OFF_KM  + (size_t)4096 * 512;        // [4096, 1024]
  size_t OFF_WBQg = OFF_V   + (size_t)4096 * 1024;       // [1024, nh*512]
  size_t OFF_WBOg = OFF_WBQg + (size_t)1024 * nh * 512;  // [nh*1024, 1024]
  size_t OFF_QM   = OFF_WBOg + (size_t)nh * 1024 * 1024; // [2048, nh*512]
  size_t OFF_O    = OFF_QM  + (size_t)2048 * nh * 512;   // [2048, nh*1024]
  size_t OFF_P    = OFF_O   + (size_t)2048 * nh * 1024;  // [nh, qc, 2048]

  dim3 blk(256);

  // --- persistent pieces: wbk, wbv, km, v ----------------------------------
  {
    int t = 1024 * 512;   // wbk
    build_wb_ip<<<(t + 255) / 256, 256, 0, stream>>>(
        w_k, blade, ws + OFF_WBK, Cc, Dd, 1, 0, 1);
    t = 1024 * 1024;      // wbv
    build_wb_full<<<(t + 255) / 256, 256, 0, stream>>>(
        w_v, blade, ws + OFF_WBV, Cc, Cc, 0, Dd);
  }
  // km = x * wbk : [4096,1024]x[1024,512]
  gemm_f32<false><<<dim3(512/TN, 4096/TM, 1), blk, 0, stream>>>(
      x, 1024, 0, ws + OFF_WBK, 512, 0, ws + OFF_KM, 512, 0, 1024, 1.0f, 0);
  // v = x * wbv : [4096,1024]x[1024,1024]
  gemm_f32<false><<<dim3(1024/TN, 4096/TM, 1), blk, 0, stream>>>(
      x, 1024, 0, ws + OFF_WBV, 1024, 0, ws + OFF_V, 1024, 0, 1024, 1.0f, 0);

  const float scale = 0.044194173824159216f;  // 1/sqrt(512)

  for (int b = 0; b < 2; b++) {
    const float* xb  = x + (size_t)b * Nn * 1024;
    const float* kmb = ws + OFF_KM + (size_t)b * Nn * 512;
    const float* vb  = ws + OFF_V  + (size_t)b * Nn * 1024;
    float* outb = out + (size_t)b * Nn * 1024;

    for (int h0 = 0; h0 < Hh; h0 += nh) {
      // head-group weight slices
      {
        int t = 1024 * nh * 512;
        build_wb_ip<<<(t + 255) / 256, 256, 0, stream>>>(
            w_q, blade, ws + OFF_WBQg, Cc, Dd, Hh, h0, nh);
        t = nh * 1024 * 1024;
        build_wb_full<<<(t + 255) / 256, 256, 0, stream>>>(
            w_o, blade, ws + OFF_WBOg, Hh * Dd, nh * Dd, h0 * Dd, Cc);
      }
      // qm_g = xb * wbq_g : [2048,1024]x[1024, nh*512]
      gemm_f32<false><<<dim3(nh*512/TN, 2048/TM, 1), blk, 0, stream>>>(
          xb, 1024, 0, ws + OFF_WBQg, nh*512, 0,
          ws + OFF_QM, nh*512, 0, 1024, 1.0f, 0);

      for (int qr0 = 0; qr0 < Nn; qr0 += qc) {
        // scores: qm chunk (head z cols at z*512) * kmb^T -> P [nh, qc, 2048]
        gemm_f32<true><<<dim3(2048/TN, qc/TM, nh), blk, 0, stream>>>(
            ws + OFF_QM + (size_t)qr0 * (nh*512), nh*512, 512,
            kmb, 512, 0,
            ws + OFF_P, 2048, (long long)qc * 2048,
            512, scale, 0);
        softmax_rows<<<nh * qc, blk, 0, stream>>>(ws + OFF_P, 2048);
        // O chunk: P * vb -> O[qr0.., z*1024..]
        gemm_f32<false><<<dim3(1024/TN, qc/TM, nh), blk, 0, stream>>>(
            ws + OFF_P, 2048, (long long)qc * 2048,
            vb, 1024, 0,
            ws + OFF_O + (size_t)qr0 * (nh*1024), nh*1024, 1024,
            2048, 1.0f, 0);
      }
      // out[b] (+)= O * wbo_g : [2048, nh*1024]x[nh*1024, 1024]
      gemm_f32<false><<<dim3(1024/TN, 2048/TM, 1), blk, 0, stream>>>(
          ws + OFF_O, nh*1024, 0, ws + OFF_WBOg, 1024, 0,
          outb, 1024, 0, nh*1024, 1.0f, h0 > 0 ? 1 : 0);
    }
  }
}

// Round 3
// 1867.934 us; speedup vs baseline: 3.6669x; 3.6669x over previous
//
#include <hip/hip_runtime.h>
#include <math.h>

// ---------------------------------------------------------------------------
// GeometricAttentionLayer: B=2, N=2048, C=64, MV=16, D=64, H=8, BLADE=9
// bf16-MFMA plan. Q/K path uses hi/lo split-bf16 (3 accumulating passes) so
// softmax argmax flips stay at fp32 level (scores sigma~3000, one-hot).
// V / PV / O-proj are single bf16 (P is one-hot -> bf16-exact).
// All GEMMs: C = A * Bt^T with A [M,K] row-major bf16, Bt [N,K] row-major
// bf16 (weights are built directly transposed; v is written transposed by
// the GEMM's transposed epilogue).
// ---------------------------------------------------------------------------

typedef __bf16 bf16x8 __attribute__((ext_vector_type(8)));
typedef float floatx4 __attribute__((ext_vector_type(4)));

__constant__ int c_ip[8] = {0, 2, 3, 4, 8, 9, 10, 14};

// ---------------------------------------------------------------------------
// Weight builds (blade contraction), written TRANSPOSED [N, K=1024 or 8192].
// ---------------------------------------------------------------------------
// wbqT/wbkT rows n = h*(D*8) + d*8 + e ; j = d*Htot + h ; y = ip[e]; hi/lo.
__global__ __launch_bounds__(256) void build_qk(
    const float* __restrict__ w, const float* __restrict__ blade,
    __bf16* __restrict__ hi, __bf16* __restrict__ lo, int Htot, int rows)
{
  int idx = blockIdx.x * 256 + threadIdx.x;
  if (idx >= rows * 1024) return;
  int kk = idx & 1023, n = idx >> 10;
  int e = n & 7, d = (n >> 3) & 63, h = n >> 9;
  int j = d * Htot + h;
  int i = kk >> 4, x = kk & 15, y = c_ip[e];
  const float* wp = w + ((size_t)j * 64 + i) * 9;
  const float* bp = blade + x * 16 + y;
  float s = 0.f;
#pragma unroll
  for (int b = 0; b < 9; b++) s += wp[b] * bp[b * 256];
  __bf16 h16 = (__bf16)s;
  hi[idx] = h16;
  lo[idx] = (__bf16)(s - (float)h16);
}

// wbvT rows n = d*16 + mv (1024), cols k = i*16+x.
__global__ __launch_bounds__(256) void build_v(
    const float* __restrict__ w, const float* __restrict__ blade,
    __bf16* __restrict__ outw)
{
  int idx = blockIdx.x * 256 + threadIdx.x;
  if (idx >= 1024 * 1024) return;
  int kk = idx & 1023, n = idx >> 10;
  int d = n >> 4, mv = n & 15;
  int i = kk >> 4, x = kk & 15;
  const float* wp = w + ((size_t)d * 64 + i) * 9;
  const float* bp = blade + x * 16 + mv;
  float s = 0.f;
#pragma unroll
  for (int b = 0; b < 9; b++) s += wp[b] * bp[b * 256];
  outw[idx] = (__bf16)s;
}

// wboT rows n = c*16 + y (1024), cols k = h*1024 + d*16 + mv (8192).
__global__ __launch_bounds__(256) void build_o(
    const float* __restrict__ w, const float* __restrict__ blade,
    __bf16* __restrict__ outw)
{
  int idx = blockIdx.x * 256 + threadIdx.x;
  if (idx >= 1024 * 8192) return;
  int kk = idx & 8191, n = idx >> 13;
  int c = n >> 4, y = n & 15;
  int h = kk >> 10, d = (kk >> 4) & 63, mv = kk & 15;
  int ich = h * 64 + d;
  const float* wp = w + ((size_t)c * 512 + ich) * 9;
  const float* bp = blade + mv * 16 + y;
  float s = 0.f;
#pragma unroll
  for (int b = 0; b < 9; b++) s += wp[b] * bp[b * 256];
  outw[idx] = (__bf16)s;
}

// f32 -> (hi, lo) bf16 split
__global__ __launch_bounds__(256) void split_f32(
    const float* __restrict__ s, __bf16* __restrict__ hi,
    __bf16* __restrict__ lo, int n)
{
  int i = blockIdx.x * 256 + threadIdx.x;
  if (i >= n) return;
  float v = s[i];
  __bf16 h = (__bf16)v;
  hi[i] = h;
  lo[i] = (__bf16)(v - (float)h);
}

// ---------------------------------------------------------------------------
// bf16 MFMA GEMM: C = alpha * A * Bt^T (+C). 128x128 tile, BK=32, 256 thr
// (4 waves, 2x2 of 64x64), mfma_f32_16x16x32_bf16, global_load_lds width 16,
// XOR-swizzled LDS (2-way only => conflict-free ds_read_b128).
// EPI: 0=f32 store, 1=f32 accumulate, 2=split hi/lo bf16, 3=bf16, 4=bf16
// transposed (C^T, ldc = M-stride). z-batch via sAz/sBz/sCz element strides.
// M,N multiples of 128 (from grid), K multiple of 32.
// ---------------------------------------------------------------------------
static __device__ __forceinline__ void gll16(const __bf16* g, __bf16* l) {
  __builtin_amdgcn_global_load_lds(
      (const __attribute__((address_space(1))) void*)g,
      (__attribute__((address_space(3))) void*)l, 16, 0, 0);
}

template <int EPI>
__global__ __launch_bounds__(256) void gemm_bf16(
    const __bf16* __restrict__ A, int lda, long long sAz,
    const __bf16* __restrict__ Bt, int ldb, long long sBz,
    void* __restrict__ C0v, void* __restrict__ C1v, int ldc, long long sCz,
    int K, float alpha)
{
  __shared__ __bf16 As[128 * 32];
  __shared__ __bf16 Bs[128 * 32];
  const int tid = threadIdx.x;
  const int wave = tid >> 6, lane = tid & 63;
  const int m0 = blockIdx.y * 128, n0 = blockIdx.x * 128;
  A  += (size_t)blockIdx.z * sAz;
  Bt += (size_t)blockIdx.z * sBz;

  // staging: chunk c = wave*2+{0,1} covers tile rows c*16..+15 (64B rows).
  // lane -> row c*16 + (lane>>2), k-chunk swizzled by row bits [2:1].
  const int srow = lane >> 2;
  const int skk = 8 * ((lane & 3) ^ ((lane >> 3) & 3));
  const __bf16* gA0 = A  + (size_t)(m0 + wave * 32      + srow) * lda + skk;
  const __bf16* gA1 = A  + (size_t)(m0 + wave * 32 + 16 + srow) * lda + skk;
  const __bf16* gB0 = Bt + (size_t)(n0 + wave * 32      + srow) * ldb + skk;
  const __bf16* gB1 = Bt + (size_t)(n0 + wave * 32 + 16 + srow) * ldb + skk;
  __bf16* lA0 = As + wave * 1024;
  __bf16* lA1 = As + wave * 1024 + 512;
  __bf16* lB0 = Bs + wave * 1024;
  __bf16* lB1 = Bs + wave * 1024 + 512;

  const int fr = lane & 15, fq = lane >> 4;
  const int wm = (wave & 1) * 64, wn = (wave >> 1) * 64;
  int aoff[4], boff[4];
#pragma unroll
  for (int t = 0; t < 4; t++) {
    int rA = wm + t * 16 + fr;
    aoff[t] = rA * 32 + 8 * (fq ^ ((rA >> 1) & 3));
    int rB = wn + t * 16 + fr;
    boff[t] = rB * 32 + 8 * (fq ^ ((rB >> 1) & 3));
  }

  floatx4 acc[4][4];
#pragma unroll
  for (int i = 0; i < 4; i++)
#pragma unroll
    for (int j = 0; j < 4; j++) acc[i][j] = (floatx4){0.f, 0.f, 0.f, 0.f};

  for (int k0 = 0; k0 < K; k0 += 32) {
    gll16(gA0, lA0); gll16(gA1, lA1);
    gll16(gB0, lB0); gll16(gB1, lB1);
    gA0 += 32; gA1 += 32; gB0 += 32; gB1 += 32;
    __syncthreads();
    bf16x8 af[4], bfv[4];
#pragma unroll
    for (int t = 0; t < 4; t++) af[t] = *(const bf16x8*)(As + aoff[t]);
#pragma unroll
    for (int t = 0; t < 4; t++) bfv[t] = *(const bf16x8*)(Bs + boff[t]);
#pragma unroll
    for (int i = 0; i < 4; i++)
#pragma unroll
      for (int j = 0; j < 4; j++)
        acc[i][j] = __builtin_amdgcn_mfma_f32_16x16x32_bf16(
            af[i], bfv[j], acc[i][j], 0, 0, 0);
    __syncthreads();
  }

  // epilogue: C/D layout col = lane&15, row = (lane>>4)*4 + reg  [m89/m91]
  const int rb = m0 + wm + fq * 4;
  const int cb = n0 + wn + fr;
#pragma unroll
  for (int i = 0; i < 4; i++) {
#pragma unroll
    for (int j = 0; j < 4; j++) {
      float v0 = acc[i][j].x * alpha, v1 = acc[i][j].y * alpha;
      float v2 = acc[i][j].z * alpha, v3 = acc[i][j].w * alpha;
      int r = rb + i * 16, c = cb + j * 16;
      if (EPI == 0 || EPI == 1) {
        float* C = (float*)C0v + (size_t)blockIdx.z * sCz;
        float* p = C + (size_t)r * ldc + c;
        if (EPI == 1) {
          v0 += p[0]; v1 += p[ldc]; v2 += p[2 * ldc]; v3 += p[3 * ldc];
        }
        p[0] = v0; p[ldc] = v1; p[2 * ldc] = v2; p[3 * ldc] = v3;
      } else if (EPI == 2) {
        __bf16* Hp = (__bf16*)C0v + (size_t)blockIdx.z * sCz;
        __bf16* Lp = (__bf16*)C1v + (size_t)blockIdx.z * sCz;
        float vv[4] = {v0, v1, v2, v3};
#pragma unroll
        for (int t = 0; t < 4; t++) {
          size_t o = (size_t)(r + t) * ldc + c;
          __bf16 hh = (__bf16)vv[t];
          Hp[o] = hh;
          Lp[o] = (__bf16)(vv[t] - (float)hh);
        }
      } else if (EPI == 3) {
        __bf16* C = (__bf16*)C0v + (size_t)blockIdx.z * sCz;
        C[(size_t)r * ldc + c] = (__bf16)v0;
        C[(size_t)(r + 1) * ldc + c] = (__bf16)v1;
        C[(size_t)(r + 2) * ldc + c] = (__bf16)v2;
        C[(size_t)(r + 3) * ldc + c] = (__bf16)v3;
      } else {  // EPI == 4: transposed bf16, CT[n][m], ldc = M-stride
        __bf16* C = (__bf16*)C0v + (size_t)blockIdx.z * sCz;
        union { __bf16 b[4]; short4 s; } u;
        u.b[0] = (__bf16)v0; u.b[1] = (__bf16)v1;
        u.b[2] = (__bf16)v2; u.b[3] = (__bf16)v3;
        *(short4*)(C + (size_t)c * ldc + r) = u.s;
      }
    }
  }
}

// ---------------------------------------------------------------------------
// Row softmax: P f32 [rows,2048] -> Pb bf16 [rows,2048].
// ---------------------------------------------------------------------------
__global__ __launch_bounds__(256) void softmax_rows_bf16(
    const float* __restrict__ P, __bf16* __restrict__ Pb)
{
  const float* p = P + (size_t)blockIdx.x * 2048;
  __bf16* q = Pb + (size_t)blockIdx.x * 2048;
  int tid = threadIdx.x;
  int wave = tid >> 6, lane = tid & 63;
  float vals[8];
  float m = -1e30f;
#pragma unroll
  for (int t = 0; t < 8; t++) {
    vals[t] = p[tid + t * 256];
    m = fmaxf(m, vals[t]);
  }
#pragma unroll
  for (int off = 32; off; off >>= 1) m = fmaxf(m, __shfl_xor(m, off, 64));
  __shared__ float red[4];
  if (lane == 0) red[wave] = m;
  __syncthreads();
  m = fmaxf(fmaxf(red[0], red[1]), fmaxf(red[2], red[3]));
  float s = 0.f;
#pragma unroll
  for (int t = 0; t < 8; t++) {
    vals[t] = expf(vals[t] - m);
    s += vals[t];
  }
#pragma unroll
  for (int off = 32; off; off >>= 1) s += __shfl_xor(s, off, 64);
  __syncthreads();
  if (lane == 0) red[wave] = s;
  __syncthreads();
  s = red[0] + red[1] + red[2] + red[3];
  float inv = 1.0f / s;
#pragma unroll
  for (int t = 0; t < 8; t++) q[tid + t * 256] = (__bf16)(vals[t] * inv);
}

// ---------------------------------------------------------------------------
extern "C" void kernel_launch(void* const* d_in, const int* in_sizes, int n_in,
                              void* d_out, int out_size, void* d_ws, size_t ws_size,
                              hipStream_t stream)
{
  (void)in_sizes; (void)n_in; (void)out_size;
  const float* x     = (const float*)d_in[0];
  const float* blade = (const float*)d_in[1];
  const float* w_q   = (const float*)d_in[2];
  const float* w_k   = (const float*)d_in[3];
  const float* w_v   = (const float*)d_in[4];
  const float* w_o   = (const float*)d_in[5];
  float* out = (float*)d_out;

  // --- buffer sizes (bytes) ------------------------------------------------
  const size_t SZ_X   = (size_t)4096 * 1024 * 2;   // xh / xl / wbqh / wbql each
  const size_t SZ_WBK = (size_t)512 * 1024 * 2;
  const size_t SZ_WBV = (size_t)1024 * 1024 * 2;
  const size_t SZ_WBO = (size_t)1024 * 8192 * 2;
  const size_t SZ_KM  = (size_t)4096 * 512 * 2;
  const size_t SZ_VT  = (size_t)1024 * 4096 * 2;
  const size_t SZ_QM  = (size_t)2048 * 4096 * 2;
  const size_t SZ_A2B = (size_t)2048 * 8192 * 2;   // per-batch A2
  const size_t SZ_PF  = (size_t)2048 * 2048 * 4;   // one head f32 scores
  const size_t SZ_PB  = (size_t)2048 * 2048 * 2;   // one head bf16 P
  const size_t SZ_QMF = (size_t)2048 * 4096 * 4;   // qm f32 staging

  const size_t fixed = 4 * SZ_X + 2 * SZ_WBK + SZ_WBV + SZ_WBO + 2 * SZ_KM +
                       SZ_VT + 2 * SZ_QM;

  // tiers: {nh, a2_full}
  int nh = 1;
  int a2full = 0;
  {
    struct { int nh, full; } tiers[] = {{8,1},{4,1},{2,1},{1,1},{1,0}};
    for (auto t : tiers) {
      size_t scr = SZ_QMF;
      size_t pscr = (size_t)t.nh * (SZ_PF + SZ_PB);
      if (pscr > scr) scr = pscr;
      size_t need = fixed + (t.full ? 2 * SZ_A2B : SZ_A2B) + scr;
      if (ws_size >= need) { nh = t.nh; a2full = t.full; break; }
      nh = t.nh; a2full = t.full;  // last tier used even if over (best effort)
    }
  }

  // --- carve workspace -----------------------------------------------------
  char* base = (char*)d_ws;
  size_t off = 0;
  auto carve = [&](size_t bytes) { char* p = base + off; off += bytes; return p; };
  __bf16* xh   = (__bf16*)carve(SZ_X);
  __bf16* xl   = (__bf16*)carve(SZ_X);
  __bf16* wbqh = (__bf16*)carve(SZ_X);
  __bf16* wbql = (__bf16*)carve(SZ_X);
  __bf16* wbkh = (__bf16*)carve(SZ_WBK);
  __bf16* wbkl = (__bf16*)carve(SZ_WBK);
  __bf16* wbv  = (__bf16*)carve(SZ_WBV);
  __bf16* wbo  = (__bf16*)carve(SZ_WBO);
  __bf16* kmh  = (__bf16*)carve(SZ_KM);
  __bf16* kml  = (__bf16*)carve(SZ_KM);
  __bf16* vT   = (__bf16*)carve(SZ_VT);
  __bf16* qmh  = (__bf16*)carve(SZ_QM);
  __bf16* qml  = (__bf16*)carve(SZ_QM);
  __bf16* A2   = (__bf16*)carve(a2full ? 2 * SZ_A2B : SZ_A2B);
  char* scratch = base + off;
  float*  Pf   = (float*)scratch;
  __bf16* Pb   = (__bf16*)(scratch + (size_t)nh * SZ_PF);
  float*  scrf = (float*)scratch;  // qm/km f32 staging (before P usage)

  dim3 blk(256);
  const float scale = 0.04419417382415922f;  // 1/sqrt(512)
  const long long PstrF = (long long)2048 * 2048;  // f32 elements per z
  const long long PstrB = (long long)2048 * 2048;  // bf16 elements per z

  // --- weight builds + x split --------------------------------------------
  build_qk<<<(4096 * 1024 + 255) / 256, blk, 0, stream>>>(w_q, blade, wbqh, wbql, 8, 4096);
  build_qk<<<(512 * 1024 + 255) / 256, blk, 0, stream>>>(w_k, blade, wbkh, wbkl, 1, 512);
  build_v<<<(1024 * 1024 + 255) / 256, blk, 0, stream>>>(w_v, blade, wbv);
  build_o<<<(1024 * 8192 + 255) / 256, blk, 0, stream>>>(w_o, blade, wbo);
  split_f32<<<(4096 * 1024 + 255) / 256, blk, 0, stream>>>(x, xh, xl, 4096 * 1024);

  // --- km (split path, 3 passes) ------------------------------------------
  gemm_bf16<0><<<dim3(4, 32, 1), blk, 0, stream>>>(
      xh, 1024, 0, wbkh, 1024, 0, scrf, nullptr, 512, 0, 1024, 1.f);
  gemm_bf16<1><<<dim3(4, 32, 1), blk, 0, stream>>>(
      xl, 1024, 0, wbkh, 1024, 0, scrf, nullptr, 512, 0, 1024, 1.f);
  gemm_bf16<1><<<dim3(4, 32, 1), blk, 0, stream>>>(
      xh, 1024, 0, wbkl, 1024, 0, scrf, nullptr, 512, 0, 1024, 1.f);
  split_f32<<<(4096 * 512 + 255) / 256, blk, 0, stream>>>(scrf, kmh, kml, 4096 * 512);

  // --- v (single bf16, transposed epilogue -> vT [1024, 4096]) ------------
  gemm_bf16<4><<<dim3(8, 32, 1), blk, 0, stream>>>(
      xh, 1024, 0, wbv, 1024, 0, vT, nullptr, 4096, 0, 1024, 1.f);

  for (int b = 0; b < 2; b++) {
    const __bf16* xhb = xh + (size_t)b * 2048 * 1024;
    const __bf16* xlb = xl + (size_t)b * 2048 * 1024;
    const __bf16* kmhb = kmh + (size_t)b * 2048 * 512;
    const __bf16* kmlb = kml + (size_t)b * 2048 * 512;

    // qm (split path, 3 passes -> f32 staging -> hi/lo)
    gemm_bf16<0><<<dim3(32, 16, 1), blk, 0, stream>>>(
        xhb, 1024, 0, wbqh, 1024, 0, scrf, nullptr, 4096, 0, 1024, 1.f);
    gemm_bf16<1><<<dim3(32, 16, 1), blk, 0, stream>>>(
        xlb, 1024, 0, wbqh, 1024, 0, scrf, nullptr, 4096, 0, 1024, 1.f);
    gemm_bf16<1><<<dim3(32, 16, 1), blk, 0, stream>>>(
        xhb, 1024, 0, wbql, 1024, 0, scrf, nullptr, 4096, 0, 1024, 1.f);
    split_f32<<<(2048 * 4096 + 255) / 256, blk, 0, stream>>>(
        scrf, qmh, qml, 2048 * 4096);

    for (int h0 = 0; h0 < 8; h0 += nh) {
      // scores: 3 passes into Pf (z = head within group)
      gemm_bf16<0><<<dim3(16, 16, nh), blk, 0, stream>>>(
          qmh + (size_t)h0 * 512, 4096, 512, kmhb, 512, 0,
          Pf, nullptr, 2048, PstrF, 512, scale);
      gemm_bf16<1><<<dim3(16, 16, nh), blk, 0, stream>>>(
          qml + (size_t)h0 * 512, 4096, 512, kmhb, 512, 0,
          Pf, nullptr, 2048, PstrF, 512, scale);
      gemm_bf16<1><<<dim3(16, 16, nh), blk, 0, stream>>>(
          qmh + (size_t)h0 * 512, 4096, 512, kmlb, 512, 0,
          Pf, nullptr, 2048, PstrF, 512, scale);
      softmax_rows_bf16<<<nh * 2048, blk, 0, stream>>>(Pf, Pb);
      // PV: Pb [z,2048,2048] * vT_b -> A2 cols (h0+z)*1024
      __bf16* a2dst = A2 + (a2full ? (size_t)b * 2048 * 8192 : (size_t)0) +
                      (size_t)h0 * 1024;
      gemm_bf16<3><<<dim3(8, 16, nh), blk, 0, stream>>>(
          Pb, 2048, PstrB, vT + (size_t)b * 2048, 4096, 0,
          a2dst, nullptr, 8192, 1024, 2048, 1.f);
    }

    if (!a2full) {
      gemm_bf16<0><<<dim3(8, 16, 1), blk, 0, stream>>>(
          A2, 8192, 0, wbo, 8192, 0,
          out + (size_t)b * 2048 * 1024, nullptr, 1024, 0, 8192, 1.f);
    }
  }

  if (a2full) {
    gemm_bf16<0><<<dim3(8, 32, 1), blk, 0, stream>>>(
        A2, 8192, 0, wbo, 8192, 0, out, nullptr, 1024, 0, 8192, 1.f);
  }
}

// Round 4
// 1357.462 us; speedup vs baseline: 5.0458x; 1.3760x over previous
//
#include <hip/hip_runtime.h>
#include <math.h>

// ---------------------------------------------------------------------------
// GeometricAttentionLayer: B=2, N=2048, C=64, MV=16, D=64, H=8, BLADE=9
// R4: fused split-bf16 GEMM (Ah*Bh + Al*Bh + Ah*Bl in one kernel, 48 MFMA per
// 32-k barrier) for the precision-critical Q/K path; split-K=4 atomic O-proj.
// ---------------------------------------------------------------------------

typedef __bf16 bf16x8 __attribute__((ext_vector_type(8)));
typedef float floatx4 __attribute__((ext_vector_type(4)));

__constant__ int c_ip[8] = {0, 2, 3, 4, 8, 9, 10, 14};

// ---------------------------------------------------------------------------
// Weight builds (blade contraction), written TRANSPOSED [N, K].
// ---------------------------------------------------------------------------
__global__ __launch_bounds__(256) void build_qk(
    const float* __restrict__ w, const float* __restrict__ blade,
    __bf16* __restrict__ hi, __bf16* __restrict__ lo, int Htot, int rows)
{
  int idx = blockIdx.x * 256 + threadIdx.x;
  if (idx >= rows * 1024) return;
  int kk = idx & 1023, n = idx >> 10;
  int e = n & 7, d = (n >> 3) & 63, h = n >> 9;
  int j = d * Htot + h;
  int i = kk >> 4, x = kk & 15, y = c_ip[e];
  const float* wp = w + ((size_t)j * 64 + i) * 9;
  const float* bp = blade + x * 16 + y;
  float s = 0.f;
#pragma unroll
  for (int b = 0; b < 9; b++) s += wp[b] * bp[b * 256];
  __bf16 h16 = (__bf16)s;
  hi[idx] = h16;
  lo[idx] = (__bf16)(s - (float)h16);
}

__global__ __launch_bounds__(256) void build_v(
    const float* __restrict__ w, const float* __restrict__ blade,
    __bf16* __restrict__ outw)
{
  int idx = blockIdx.x * 256 + threadIdx.x;
  if (idx >= 1024 * 1024) return;
  int kk = idx & 1023, n = idx >> 10;
  int d = n >> 4, mv = n & 15;
  int i = kk >> 4, x = kk & 15;
  const float* wp = w + ((size_t)d * 64 + i) * 9;
  const float* bp = blade + x * 16 + mv;
  float s = 0.f;
#pragma unroll
  for (int b = 0; b < 9; b++) s += wp[b] * bp[b * 256];
  outw[idx] = (__bf16)s;
}

__global__ __launch_bounds__(256) void build_o(
    const float* __restrict__ w, const float* __restrict__ blade,
    __bf16* __restrict__ outw)
{
  int idx = blockIdx.x * 256 + threadIdx.x;
  if (idx >= 1024 * 8192) return;
  int kk = idx & 8191, n = idx >> 13;
  int c = n >> 4, y = n & 15;
  int h = kk >> 10, d = (kk >> 4) & 63, mv = kk & 15;
  int ich = h * 64 + d;
  const float* wp = w + ((size_t)c * 512 + ich) * 9;
  const float* bp = blade + mv * 16 + y;
  float s = 0.f;
#pragma unroll
  for (int b = 0; b < 9; b++) s += wp[b] * bp[b * 256];
  outw[idx] = (__bf16)s;
}

__global__ __launch_bounds__(256) void split_f32(
    const float* __restrict__ s, __bf16* __restrict__ hi,
    __bf16* __restrict__ lo, int n)
{
  int i = blockIdx.x * 256 + threadIdx.x;
  if (i >= n) return;
  float v = s[i];
  __bf16 h = (__bf16)v;
  hi[i] = h;
  lo[i] = (__bf16)(v - (float)h);
}

// ---------------------------------------------------------------------------
static __device__ __forceinline__ void gll16(const __bf16* g, __bf16* l) {
  __builtin_amdgcn_global_load_lds(
      (const __attribute__((address_space(1))) void*)g,
      (__attribute__((address_space(3))) void*)l, 16, 0, 0);
}

// ---------------------------------------------------------------------------
// Plain bf16 MFMA GEMM: C = alpha * A * Bt^T. 128x128, BK=32, 256 thr.
// EPI: 0=f32 store, 3=bf16, 4=bf16 transposed, 5=f32 atomicAdd.
// ---------------------------------------------------------------------------
template <int EPI>
__global__ __launch_bounds__(256) void gemm_bf16(
    const __bf16* __restrict__ A, int lda, long long sAz,
    const __bf16* __restrict__ Bt, int ldb, long long sBz,
    void* __restrict__ C0v, int ldc, long long sCz,
    int K, float alpha)
{
  __shared__ __bf16 As[128 * 32];
  __shared__ __bf16 Bs[128 * 32];
  const int tid = threadIdx.x;
  const int wave = tid >> 6, lane = tid & 63;
  const int m0 = blockIdx.y * 128, n0 = blockIdx.x * 128;
  A  += (size_t)blockIdx.z * sAz;
  Bt += (size_t)blockIdx.z * sBz;

  const int srow = lane >> 2;
  const int skk = 8 * ((lane & 3) ^ ((lane >> 3) & 3));
  const __bf16* gA0 = A  + (size_t)(m0 + wave * 32      + srow) * lda + skk;
  const __bf16* gA1 = A  + (size_t)(m0 + wave * 32 + 16 + srow) * lda + skk;
  const __bf16* gB0 = Bt + (size_t)(n0 + wave * 32      + srow) * ldb + skk;
  const __bf16* gB1 = Bt + (size_t)(n0 + wave * 32 + 16 + srow) * ldb + skk;
  __bf16* lA0 = As + wave * 1024;
  __bf16* lA1 = As + wave * 1024 + 512;
  __bf16* lB0 = Bs + wave * 1024;
  __bf16* lB1 = Bs + wave * 1024 + 512;

  const int fr = lane & 15, fq = lane >> 4;
  const int wm = (wave & 1) * 64, wn = (wave >> 1) * 64;
  int aoff[4], boff[4];
#pragma unroll
  for (int t = 0; t < 4; t++) {
    int rA = wm + t * 16 + fr;
    aoff[t] = rA * 32 + 8 * (fq ^ ((rA >> 1) & 3));
    int rB = wn + t * 16 + fr;
    boff[t] = rB * 32 + 8 * (fq ^ ((rB >> 1) & 3));
  }

  floatx4 acc[4][4];
#pragma unroll
  for (int i = 0; i < 4; i++)
#pragma unroll
    for (int j = 0; j < 4; j++) acc[i][j] = (floatx4){0.f, 0.f, 0.f, 0.f};

  for (int k0 = 0; k0 < K; k0 += 32) {
    gll16(gA0, lA0); gll16(gA1, lA1);
    gll16(gB0, lB0); gll16(gB1, lB1);
    gA0 += 32; gA1 += 32; gB0 += 32; gB1 += 32;
    __syncthreads();
    bf16x8 af[4], bfv[4];
#pragma unroll
    for (int t = 0; t < 4; t++) af[t] = *(const bf16x8*)(As + aoff[t]);
#pragma unroll
    for (int t = 0; t < 4; t++) bfv[t] = *(const bf16x8*)(Bs + boff[t]);
#pragma unroll
    for (int i = 0; i < 4; i++)
#pragma unroll
      for (int j = 0; j < 4; j++)
        acc[i][j] = __builtin_amdgcn_mfma_f32_16x16x32_bf16(
            af[i], bfv[j], acc[i][j], 0, 0, 0);
    __syncthreads();
  }

  const int rb = m0 + wm + fq * 4;
  const int cb = n0 + wn + fr;
#pragma unroll
  for (int i = 0; i < 4; i++) {
#pragma unroll
    for (int j = 0; j < 4; j++) {
      float v0 = acc[i][j].x * alpha, v1 = acc[i][j].y * alpha;
      float v2 = acc[i][j].z * alpha, v3 = acc[i][j].w * alpha;
      int r = rb + i * 16, c = cb + j * 16;
      if (EPI == 0) {
        float* C = (float*)C0v + (size_t)blockIdx.z * sCz;
        float* p = C + (size_t)r * ldc + c;
        p[0] = v0; p[ldc] = v1; p[2 * ldc] = v2; p[3 * ldc] = v3;
      } else if (EPI == 3) {
        __bf16* C = (__bf16*)C0v + (size_t)blockIdx.z * sCz;
        C[(size_t)r * ldc + c] = (__bf16)v0;
        C[(size_t)(r + 1) * ldc + c] = (__bf16)v1;
        C[(size_t)(r + 2) * ldc + c] = (__bf16)v2;
        C[(size_t)(r + 3) * ldc + c] = (__bf16)v3;
      } else if (EPI == 4) {  // transposed bf16, CT[n][m], ldc = M-stride
        __bf16* C = (__bf16*)C0v + (size_t)blockIdx.z * sCz;
        union { __bf16 b[4]; short4 s; } u;
        u.b[0] = (__bf16)v0; u.b[1] = (__bf16)v1;
        u.b[2] = (__bf16)v2; u.b[3] = (__bf16)v3;
        *(short4*)(C + (size_t)c * ldc + r) = u.s;
      } else {  // EPI == 5: f32 atomic accumulate (split-K)
        float* C = (float*)C0v + (size_t)blockIdx.z * sCz;
        float* p = C + (size_t)r * ldc + c;
        atomicAdd(p + 0 * ldc, v0);
        atomicAdd(p + 1 * ldc, v1);
        atomicAdd(p + 2 * ldc, v2);
        atomicAdd(p + 3 * ldc, v3);
      }
    }
  }
}

// ---------------------------------------------------------------------------
// Fused split-bf16 GEMM: C = alpha * (Ah*Bh^T + Al*Bh^T + Ah*Bl^T).
// 48 MFMA per 32-k step. EPI: 0=f32 store, 2=split hi/lo bf16 store.
// ---------------------------------------------------------------------------
template <int EPI>
__global__ __launch_bounds__(256) void gemm_split(
    const __bf16* __restrict__ Ah, const __bf16* __restrict__ Al, int lda, long long sAz,
    const __bf16* __restrict__ Bh, const __bf16* __restrict__ Bl, int ldb, long long sBz,
    void* __restrict__ C0v, void* __restrict__ C1v, int ldc, long long sCz,
    int K, float alpha)
{
  __shared__ __bf16 Ash[128 * 32];
  __shared__ __bf16 Asl[128 * 32];
  __shared__ __bf16 Bsh[128 * 32];
  __shared__ __bf16 Bsl[128 * 32];
  const int tid = threadIdx.x;
  const int wave = tid >> 6, lane = tid & 63;
  const int m0 = blockIdx.y * 128, n0 = blockIdx.x * 128;
  Ah += (size_t)blockIdx.z * sAz;
  Al += (size_t)blockIdx.z * sAz;
  Bh += (size_t)blockIdx.z * sBz;
  Bl += (size_t)blockIdx.z * sBz;

  const int srow = lane >> 2;
  const int skk = 8 * ((lane & 3) ^ ((lane >> 3) & 3));
  const size_t ao0 = (size_t)(m0 + wave * 32      + srow) * lda + skk;
  const size_t ao1 = (size_t)(m0 + wave * 32 + 16 + srow) * lda + skk;
  const size_t bo0 = (size_t)(n0 + wave * 32      + srow) * ldb + skk;
  const size_t bo1 = (size_t)(n0 + wave * 32 + 16 + srow) * ldb + skk;
  const __bf16 *gAh0 = Ah + ao0, *gAh1 = Ah + ao1;
  const __bf16 *gAl0 = Al + ao0, *gAl1 = Al + ao1;
  const __bf16 *gBh0 = Bh + bo0, *gBh1 = Bh + bo1;
  const __bf16 *gBl0 = Bl + bo0, *gBl1 = Bl + bo1;
  __bf16* lw0 = Ash + wave * 1024;       // chunk base offsets shared by all 4
  __bf16* lw1 = Ash + wave * 1024 + 512;
  const int ldsoff = (int)(lw0 - Ash);

  const int fr = lane & 15, fq = lane >> 4;
  const int wm = (wave & 1) * 64, wn = (wave >> 1) * 64;
  int aoff[4], boff[4];
#pragma unroll
  for (int t = 0; t < 4; t++) {
    int rA = wm + t * 16 + fr;
    aoff[t] = rA * 32 + 8 * (fq ^ ((rA >> 1) & 3));
    int rB = wn + t * 16 + fr;
    boff[t] = rB * 32 + 8 * (fq ^ ((rB >> 1) & 3));
  }

  floatx4 acc[4][4];
#pragma unroll
  for (int i = 0; i < 4; i++)
#pragma unroll
    for (int j = 0; j < 4; j++) acc[i][j] = (floatx4){0.f, 0.f, 0.f, 0.f};

  for (int k0 = 0; k0 < K; k0 += 32) {
    gll16(gAh0, Ash + ldsoff); gll16(gAh1, Ash + ldsoff + 512);
    gll16(gAl0, Asl + ldsoff); gll16(gAl1, Asl + ldsoff + 512);
    gll16(gBh0, Bsh + ldsoff); gll16(gBh1, Bsh + ldsoff + 512);
    gll16(gBl0, Bsl + ldsoff); gll16(gBl1, Bsl + ldsoff + 512);
    gAh0 += 32; gAh1 += 32; gAl0 += 32; gAl1 += 32;
    gBh0 += 32; gBh1 += 32; gBl0 += 32; gBl1 += 32;
    __syncthreads();
    bf16x8 afh[4], afl[4], bfh[4], bfl[4];
#pragma unroll
    for (int t = 0; t < 4; t++) {
      afh[t] = *(const bf16x8*)(Ash + aoff[t]);
      afl[t] = *(const bf16x8*)(Asl + aoff[t]);
      bfh[t] = *(const bf16x8*)(Bsh + boff[t]);
      bfl[t] = *(const bf16x8*)(Bsl + boff[t]);
    }
#pragma unroll
    for (int i = 0; i < 4; i++)
#pragma unroll
      for (int j = 0; j < 4; j++) {
        acc[i][j] = __builtin_amdgcn_mfma_f32_16x16x32_bf16(
            afh[i], bfh[j], acc[i][j], 0, 0, 0);
        acc[i][j] = __builtin_amdgcn_mfma_f32_16x16x32_bf16(
            afl[i], bfh[j], acc[i][j], 0, 0, 0);
        acc[i][j] = __builtin_amdgcn_mfma_f32_16x16x32_bf16(
            afh[i], bfl[j], acc[i][j], 0, 0, 0);
      }
    __syncthreads();
  }

  const int rb = m0 + wm + fq * 4;
  const int cb = n0 + wn + fr;
#pragma unroll
  for (int i = 0; i < 4; i++) {
#pragma unroll
    for (int j = 0; j < 4; j++) {
      float vv[4] = {acc[i][j].x * alpha, acc[i][j].y * alpha,
                     acc[i][j].z * alpha, acc[i][j].w * alpha};
      int r = rb + i * 16, c = cb + j * 16;
      if (EPI == 0) {
        float* C = (float*)C0v + (size_t)blockIdx.z * sCz;
        float* p = C + (size_t)r * ldc + c;
        p[0] = vv[0]; p[ldc] = vv[1]; p[2 * ldc] = vv[2]; p[3 * ldc] = vv[3];
      } else {  // EPI == 2: split hi/lo
        __bf16* Hp = (__bf16*)C0v + (size_t)blockIdx.z * sCz;
        __bf16* Lp = (__bf16*)C1v + (size_t)blockIdx.z * sCz;
#pragma unroll
        for (int t = 0; t < 4; t++) {
          size_t o = (size_t)(r + t) * ldc + c;
          __bf16 hh = (__bf16)vv[t];
          Hp[o] = hh;
          Lp[o] = (__bf16)(vv[t] - (float)hh);
        }
      }
    }
  }
}

// ---------------------------------------------------------------------------
// Row softmax: P f32 [rows,2048] -> Pb bf16 [rows,2048].
// ---------------------------------------------------------------------------
__global__ __launch_bounds__(256) void softmax_rows_bf16(
    const float* __restrict__ P, __bf16* __restrict__ Pb)
{
  const float* p = P + (size_t)blockIdx.x * 2048;
  __bf16* q = Pb + (size_t)blockIdx.x * 2048;
  int tid = threadIdx.x;
  int wave = tid >> 6, lane = tid & 63;
  float vals[8];
  float m = -1e30f;
#pragma unroll
  for (int t = 0; t < 8; t++) {
    vals[t] = p[tid + t * 256];
    m = fmaxf(m, vals[t]);
  }
#pragma unroll
  for (int off = 32; off; off >>= 1) m = fmaxf(m, __shfl_xor(m, off, 64));
  __shared__ float red[4];
  if (lane == 0) red[wave] = m;
  __syncthreads();
  m = fmaxf(fmaxf(red[0], red[1]), fmaxf(red[2], red[3]));
  float s = 0.f;
#pragma unroll
  for (int t = 0; t < 8; t++) {
    vals[t] = expf(vals[t] - m);
    s += vals[t];
  }
#pragma unroll
  for (int off = 32; off; off >>= 1) s += __shfl_xor(s, off, 64);
  __syncthreads();
  if (lane == 0) red[wave] = s;
  __syncthreads();
  s = red[0] + red[1] + red[2] + red[3];
  float inv = 1.0f / s;
#pragma unroll
  for (int t = 0; t < 8; t++) q[tid + t * 256] = (__bf16)(vals[t] * inv);
}

// ---------------------------------------------------------------------------
extern "C" void kernel_launch(void* const* d_in, const int* in_sizes, int n_in,
                              void* d_out, int out_size, void* d_ws, size_t ws_size,
                              hipStream_t stream)
{
  (void)in_sizes; (void)n_in;
  const float* x     = (const float*)d_in[0];
  const float* blade = (const float*)d_in[1];
  const float* w_q   = (const float*)d_in[2];
  const float* w_k   = (const float*)d_in[3];
  const float* w_v   = (const float*)d_in[4];
  const float* w_o   = (const float*)d_in[5];
  float* out = (float*)d_out;

  // --- buffer sizes (bytes) ------------------------------------------------
  const size_t SZ_X    = (size_t)4096 * 1024 * 2;   // xh/xl/wbqh/wbql each
  const size_t SZ_WBK  = (size_t)512 * 1024 * 2;
  const size_t SZ_WBV  = (size_t)1024 * 1024 * 2;
  const size_t SZ_WBO  = (size_t)1024 * 8192 * 2;
  const size_t SZ_KM   = (size_t)4096 * 512 * 2;
  const size_t SZ_VT   = (size_t)1024 * 4096 * 2;
  const size_t SZ_QMB  = (size_t)2048 * 4096 * 2;   // per-batch qm (hi or lo)
  const size_t SZ_A2B  = (size_t)2048 * 8192 * 2;   // per-batch A2
  const size_t SZ_PF   = (size_t)2048 * 2048 * 4;   // one head f32 scores
  const size_t SZ_PB   = (size_t)2048 * 2048 * 2;   // one head bf16 P

  const size_t fixed0 = 4 * SZ_X + 2 * SZ_WBK + SZ_WBV + SZ_WBO + 2 * SZ_KM + SZ_VT;

  // tiers: {nh, a2full, qmfull}
  int nh = 1, a2full = 0, qmfull = 0;
  {
    struct { int nh, a2, qm; } tiers[] = {{8,1,1},{4,1,1},{2,1,1},{1,1,1},{1,0,0}};
    for (auto t : tiers) {
      size_t need = fixed0 + 2 * (t.qm ? 2 * SZ_QMB : SZ_QMB) +
                    (t.a2 ? 2 * SZ_A2B : SZ_A2B) +
                    (size_t)t.nh * (SZ_PF + SZ_PB);
      nh = t.nh; a2full = t.a2; qmfull = t.qm;
      if (ws_size >= need) break;
    }
  }

  // --- carve workspace -----------------------------------------------------
  char* base = (char*)d_ws;
  size_t off = 0;
  auto carve = [&](size_t bytes) { char* p = base + off; off += bytes; return p; };
  __bf16* xh   = (__bf16*)carve(SZ_X);
  __bf16* xl   = (__bf16*)carve(SZ_X);
  __bf16* wbqh = (__bf16*)carve(SZ_X);
  __bf16* wbql = (__bf16*)carve(SZ_X);
  __bf16* wbkh = (__bf16*)carve(SZ_WBK);
  __bf16* wbkl = (__bf16*)carve(SZ_WBK);
  __bf16* wbv  = (__bf16*)carve(SZ_WBV);
  __bf16* wbo  = (__bf16*)carve(SZ_WBO);
  __bf16* kmh  = (__bf16*)carve(SZ_KM);
  __bf16* kml  = (__bf16*)carve(SZ_KM);
  __bf16* vT   = (__bf16*)carve(SZ_VT);
  __bf16* qmh  = (__bf16*)carve(qmfull ? 2 * SZ_QMB : SZ_QMB);
  __bf16* qml  = (__bf16*)carve(qmfull ? 2 * SZ_QMB : SZ_QMB);
  __bf16* A2   = (__bf16*)carve(a2full ? 2 * SZ_A2B : SZ_A2B);
  float*  Pf   = (float*)carve((size_t)nh * SZ_PF);
  __bf16* Pb   = (__bf16*)carve((size_t)nh * SZ_PB);

  dim3 blk(256);
  const float scale = 0.04419417382415922f;  // 1/sqrt(512)

  // --- weight builds + x split --------------------------------------------
  build_qk<<<(4096 * 1024 + 255) / 256, blk, 0, stream>>>(w_q, blade, wbqh, wbql, 8, 4096);
  build_qk<<<(512 * 1024 + 255) / 256, blk, 0, stream>>>(w_k, blade, wbkh, wbkl, 1, 512);
  build_v<<<(1024 * 1024 + 255) / 256, blk, 0, stream>>>(w_v, blade, wbv);
  build_o<<<(1024 * 8192 + 255) / 256, blk, 0, stream>>>(w_o, blade, wbo);
  split_f32<<<(4096 * 1024 + 255) / 256, blk, 0, stream>>>(x, xh, xl, 4096 * 1024);

  // km: fused split, direct hi/lo store  [4096,1024]x[512,1024]^T
  gemm_split<2><<<dim3(4, 32, 1), blk, 0, stream>>>(
      xh, xl, 1024, 0, wbkh, wbkl, 1024, 0, kmh, kml, 512, 0, 1024, 1.f);

  // v: plain bf16, transposed epilogue -> vT [1024, 4096]
  gemm_bf16<4><<<dim3(8, 32, 1), blk, 0, stream>>>(
      xh, 1024, 0, wbv, 1024, 0, vT, 4096, 0, 1024, 1.f);

  // qm: fused split, both batches if qmfull
  if (qmfull) {
    gemm_split<2><<<dim3(32, 32, 1), blk, 0, stream>>>(
        xh, xl, 1024, 0, wbqh, wbql, 1024, 0, qmh, qml, 4096, 0, 1024, 1.f);
  }

  // zero out (atomic split-K target)
  hipMemsetAsync(d_out, 0, (size_t)out_size * sizeof(float), stream);

  for (int b = 0; b < 2; b++) {
    const __bf16* kmhb = kmh + (size_t)b * 2048 * 512;
    const __bf16* kmlb = kml + (size_t)b * 2048 * 512;
    size_t qoff = qmfull ? (size_t)b * 2048 * 4096 : 0;

    if (!qmfull) {
      gemm_split<2><<<dim3(32, 16, 1), blk, 0, stream>>>(
          xh + (size_t)b * 2048 * 1024, xl + (size_t)b * 2048 * 1024, 1024, 0,
          wbqh, wbql, 1024, 0, qmh, qml, 4096, 0, 1024, 1.f);
    }

    for (int h0 = 0; h0 < 8; h0 += nh) {
      // scores: fused split, z = head in group
      gemm_split<0><<<dim3(16, 16, nh), blk, 0, stream>>>(
          qmh + qoff + (size_t)h0 * 512, qml + qoff + (size_t)h0 * 512, 4096, 512,
          kmhb, kmlb, 512, 0,
          Pf, nullptr, 2048, (long long)2048 * 2048, 512, scale);
      softmax_rows_bf16<<<nh * 2048, blk, 0, stream>>>(Pf, Pb);
      // PV: Pb [z,2048,2048] * vT_b^T -> A2 cols (h0+z)*1024
      __bf16* a2dst = A2 + (a2full ? (size_t)b * 2048 * 8192 : (size_t)0) +
                      (size_t)h0 * 1024;
      gemm_bf16<3><<<dim3(8, 16, nh), blk, 0, stream>>>(
          Pb, 2048, (long long)2048 * 2048, vT + (size_t)b * 2048, 4096, 0,
          a2dst, 8192, 1024, 2048, 1.f);
    }

    if (!a2full) {
      // O-proj per batch, split-K=4, atomic accumulate into out
      gemm_bf16<5><<<dim3(8, 16, 4), blk, 0, stream>>>(
          A2, 8192, 2048, wbo, 8192, 2048,
          out + (size_t)b * 2048 * 1024, 1024, 0, 2048, 1.f);
    }
  }

  if (a2full) {
    // O-proj both batches, split-K=4 via z (A/B advance 2048 in K per z)
    gemm_bf16<5><<<dim3(8, 32, 4), blk, 0, stream>>>(
        A2, 8192, 2048, wbo, 8192, 2048, out, 1024, 0, 2048, 1.f);
  }
}